// Round 1
// baseline (368.261 us; speedup 1.0000x reference)
//
#include <hip/hip_runtime.h>

// SSIM loss, two-pass separable conv through LDS. 96 planes of 512x512,
// 64x64 output tile per block, 512 threads.
//
// R5 changes (vs R4 single-pass):
//  * True two-pass separable convolution. R4 recomputed the horizontal
//    conv per thread, amortized only over RPT=4 rows -> 120 pk-ops/px
//    vs ~49 algorithmic floor. Now:
//      Pass 1: vertical conv (global -> LDS). Unit = (column, 8-row seg),
//              74 cols x 8 segs = 592 units; lane-per-column keeps global
//              reads coalesced. Each h element computed ONCE.
//      Pass 2: horizontal conv (LDS -> regs) + SSIM formula + reduce.
//              Thread = (row, 8-col seg); 18 contiguous b128 reads.
//    pk-FMA/tile: ~492K -> ~205K (2.4x); LDS b128 wave-instrs/tile:
//    ~672 -> ~220 (3x).
//  * h buffer [64][stride 75] of float4 {vA.s, vA.d, vB.s2, vB.d2}.
//    Stride 75 (odd, 75%8==3) -> bank-quad (3*row+col)%8 distinct within
//    every 8-lane phase group: conflict-free b128 reads AND writes.
//  * LDS 76.8 KB -> 2 blocks/CU = 16 waves/CU; amdgpu_waves_per_eu(4,4)
//    caps allocator at 128 VGPRs.

typedef float v2f __attribute__((ext_vector_type(2)));
typedef float v4f __attribute__((ext_vector_type(4)));

#define IMG 512
#define TILE 64
#define HALO 5
#define HCOLS 74            // TILE + 2*HALO columns of h
#define HSTRIDE 75          // in float4 units; odd -> conflict-free
#define SEGS 8              // pass-1 row segments
#define RPT1 8              // output rows per pass-1 unit
#define NPIX 25165824.0     // 32*3*512*512

// Gaussian(sigma=1.5, 11 taps), normalized, fp32 (verified in R1-R4)
__device__ constexpr float WT[11] = {
    0.00102838f, 0.00759876f, 0.03600077f, 0.10936068f, 0.21300552f,
    0.26601173f,
    0.21300552f, 0.10936068f, 0.03600077f, 0.00759876f, 0.00102838f};

__global__ __launch_bounds__(512)
__attribute__((amdgpu_waves_per_eu(4, 4)))
void ssim_main(const float* __restrict__ clean,
               const float* __restrict__ adv,
               double* __restrict__ accum)
{
    // h[row][col]: float4 {convV(s), convV(d), convV(s^2), convV(d^2)}
    __shared__ __align__(16) v4f hbuf[TILE * HSTRIDE];   // 76,800 B
    __shared__ float wpart[8];

    const int tid = threadIdx.x;
    const int b = blockIdx.x;
    const int plane = b >> 6;         // 64 tiles per plane
    const int t6 = b & 63;
    const int tile_x = (t6 & 7) * TILE;
    const int tile_y = (t6 >> 3) * TILE;

    const float* __restrict__ cp = clean + (size_t)plane * (IMG * IMG);
    const float* __restrict__ ap = adv   + (size_t)plane * (IMG * IMG);

    // ---- Pass 1: vertical conv, global -> LDS ----
    // unit u: seg = u/74 (rows seg*8..seg*8+7), uc = u%74 (image col
    // tile_x + uc - 5). Consecutive threads -> consecutive columns ->
    // coalesced global loads. Threads 0..79 take a second unit.
    for (int u = tid; u < HCOLS * SEGS; u += 512) {
        const int seg = u / HCOLS;
        const int uc  = u - seg * HCOLS;
        const int col = tile_x + uc - HALO;
        const bool cvalid = ((unsigned)col < IMG);
        const int or0 = seg * RPT1;           // first output row (tile coords)

        v2f accA[RPT1], accB[RPT1];
        #pragma unroll
        for (int o = 0; o < RPT1; ++o) {
            accA[o] = (v2f){0.f, 0.f};
            accB[o] = (v2f){0.f, 0.f};
        }

        #pragma unroll
        for (int j = 0; j < RPT1 + 10; ++j) {
            const int gr = tile_y + or0 - HALO + j;
            v2f t = {0.f, 0.f};
            if (cvalid && (unsigned)gr < IMG) {
                const int gi = gr * IMG + col;
                const float x = cp[gi];
                const float y = ap[gi];
                t.x = x + y;                  // s
                t.y = x - y;                  // d
            }
            const v2f p = t * t;              // {s^2, d^2}
            #pragma unroll
            for (int o = 0; o < RPT1; ++o) {
                const int kv = j - o;
                if (kv >= 0 && kv < 11) {
                    const float w = WT[kv];
                    accA[o] += w * t;
                    accB[o] += w * p;
                }
            }
        }

        #pragma unroll
        for (int o = 0; o < RPT1; ++o) {
            hbuf[(or0 + o) * HSTRIDE + uc] =
                (v4f){accA[o].x, accA[o].y, accB[o].x, accB[o].y};
        }
    }
    __syncthreads();

    // ---- Pass 2: horizontal conv, LDS -> regs, + SSIM + reduce ----
    // thread: row = tid&63, col-seg = tid>>6 (8 output cols each).
    // Wave = 64 consecutive rows, same seg: bank-quad (3*row + c)%8
    // distinct per 8-lane phase -> conflict-free b128 reads.
    const int row = tid & 63;
    const int cs  = tid >> 6;                 // 0..7
    const int c0  = cs * 8;                   // output cols c0..c0+7
    const v4f* __restrict__ hrow = hbuf + row * HSTRIDE + c0;

    v2f A[8], B[8];
    #pragma unroll
    for (int o = 0; o < 8; ++o) {
        A[o] = (v2f){0.f, 0.f};
        B[o] = (v2f){0.f, 0.f};
    }

    #pragma unroll
    for (int k = 0; k < 18; ++k) {            // h cols c0+k, k=0..17
        const v4f h = hrow[k];
        const v2f hA = {h.x, h.y};
        const v2f hB = {h.z, h.w};
        #pragma unroll
        for (int o = 0; o < 8; ++o) {
            const int kh = k - o;
            if (kh >= 0 && kh < 11) {
                const float w = WT[kh];
                A[o] += w * hA;
                B[o] += w * hB;
            }
        }
    }

    // u=conv2(s), v=conv2(d), P=conv2(s^2), Q=conv2(d^2), U=u^2, V=v^2:
    //   2*mu12        = (U-V)/2        mu1^2+mu2^2  = (U+V)/2
    //   2*sigma12     = (P-Q)/2-(U-V)/2
    //   sig1^2+sig2^2 = (P+Q)/2-(U+V)/2
    const float C1 = 1e-4f;   // 0.01^2
    const float C2 = 9e-4f;   // 0.03^2
    float lsum = 0.f;
    #pragma unroll
    for (int o = 0; o < 8; ++o) {
        const float U = A[o].x * A[o].x;
        const float V = A[o].y * A[o].y;
        const float halfUmV = 0.5f * (U - V);
        const float halfUpV = 0.5f * (U + V);
        const float num1 = halfUmV + C1;
        const float num2 = 0.5f * (B[o].x - B[o].y) - halfUmV + C2;
        const float den1 = halfUpV + C1;
        const float den2 = 0.5f * (B[o].x + B[o].y) - halfUpV + C2;
        lsum += (num1 * num2) * __builtin_amdgcn_rcpf(den1 * den2);
    }

    // ---- Reduce: wave shuffle -> LDS -> one atomic per block ----
    #pragma unroll
    for (int off = 32; off > 0; off >>= 1)
        lsum += __shfl_down(lsum, off);
    const int lane = tid & 63;
    const int wave = tid >> 6;                // 0..7
    if (lane == 0) wpart[wave] = lsum;
    __syncthreads();
    if (tid == 0) {
        float bs = 0.f;
        #pragma unroll
        for (int w = 0; w < 8; ++w) bs += wpart[w];
        atomicAdd(accum, (double)bs);
    }
}

__global__ void ssim_finalize(const double* __restrict__ accum,
                              float* __restrict__ out)
{
    if (threadIdx.x == 0) {
        out[0] = 1.f - (float)(accum[0] / NPIX);
    }
}

extern "C" void kernel_launch(void* const* d_in, const int* in_sizes, int n_in,
                              void* d_out, int out_size, void* d_ws, size_t ws_size,
                              hipStream_t stream)
{
    const float* clean = (const float*)d_in[0];
    const float* adv   = (const float*)d_in[1];
    float* out = (float*)d_out;
    double* accum = (double*)d_ws;

    hipMemsetAsync(accum, 0, sizeof(double), stream);

    const int nblocks = 96 * 64;   // 96 planes * (8x8 tiles of 64x64)
    ssim_main<<<nblocks, 512, 0, stream>>>(clean, adv, accum);
    ssim_finalize<<<1, 64, 0, stream>>>(accum, out);
}